// Round 1
// 224.622 us; speedup vs baseline: 1.0003x; 1.0003x over previous
//
#include <hip/hip_runtime.h>
#include <hip/hip_bf16.h>

typedef unsigned short u16;
typedef unsigned int u32;
typedef __attribute__((ext_vector_type(8))) short short8;   // 8 bf16 (4 VGPRs) MFMA operand
typedef __attribute__((ext_vector_type(4))) float f32x4;    // MFMA 16x16 accumulator

#define T_TOK 32768
#define SCALE_ATT 0.17677669529663687f   // 32^-0.5

__device__ __forceinline__ u16 f2bf(float f){
  u32 u = __float_as_uint(f);
  u32 r = u + 0x7fffu + ((u >> 16) & 1u);   // RTN-even
  return (u16)(r >> 16);
}
__device__ __forceinline__ float bf2f(u16 h){
  return __uint_as_float(((u32)h) << 16);
}

// ---------------- fp32 -> bf16 convert (qkv_w, proj_w) ----------------
__global__ void k_cvt(const float* __restrict__ s, u16* __restrict__ d, int n4){
  int i = blockIdx.x * blockDim.x + threadIdx.x;
  if (i < n4){
    float4 v = ((const float4*)s)[i];
    ushort4 o;
    o.x = f2bf(v.x); o.y = f2bf(v.y); o.z = f2bf(v.z); o.w = f2bf(v.w);
    ((ushort4*)d)[i] = o;
  }
}

// split fp32 -> (hi, lo) bf16 pair: v = hi + lo + O(2^-18 v). For router w1.
__global__ void k_cvt_split(const float* __restrict__ s, u16* __restrict__ hi,
                            u16* __restrict__ lo, int n){
  int i = blockIdx.x * blockDim.x + threadIdx.x;
  if (i < n){
    float v = s[i];
    u16 h = f2bf(v);
    hi[i] = h;
    lo[i] = f2bf(v - bf2f(h));    // v - hi exact in fp32 (shared high bits)
  }
}

__global__ void k_init(int* counts, int* cursors){
  int t = threadIdx.x;
  if (t < 8){ counts[t] = 0; cursors[t] = 0; }
}

// ---------------- MFMA router (split-bf16 "bf16x3") ----------------
// h = relu(x@w1^T+b1) via MFMA: x=x_hi+x_lo, w1=w1_hi+w1_lo (bf16 pairs);
// h ~ hi*hi + hi*lo + lo*hi in fp32 accum -> logit err ~1e-6 << top-2 gap.
__global__ __launch_bounds__(256) void k_router(
    const float* __restrict__ x, const u16* __restrict__ w1h, const u16* __restrict__ w1l,
    const float* __restrict__ b1, const float* __restrict__ w2, const float* __restrict__ b2,
    int* __restrict__ routes, float* __restrict__ pmax, int* __restrict__ counts,
    u16* __restrict__ x_bf)
{
  __shared__ __align__(16) char smem[64*132*4];   // 33792 B
  u16* Ah = (u16*)smem;          // 64 x 40
  u16* Al = Ah + 2560;           // 64 x 40
  u16* Bh = Al + 2560;           // 128 x 40
  u16* Bl = Bh + 5120;           // 128 x 40
  float* Hs = (float*)smem;      // overlay after MFMA: 64 x 132
  __shared__ int lhist[8];

  int tid = threadIdx.x;
  int t0 = blockIdx.x * 64;
  int wv = tid >> 6, lane = tid & 63, quad = lane >> 4, l16 = lane & 15;
  if (tid < 8) lhist[tid] = 0;

  int arow = tid >> 2, acg = tid & 3;        // A staging: 64 rows x 4 col-groups of 8
  int brow = tid >> 1, bhalf = tid & 1;      // B staging: 128 rows x 2 halves of 16

  f32x4 acc[4][2];
  #pragma unroll
  for (int i = 0; i < 4; ++i)
    #pragma unroll
    for (int j = 0; j < 2; ++j)
      #pragma unroll
      for (int rr = 0; rr < 4; ++rr) acc[i][j][rr] = 0.f;

  for (int kt = 0; kt < 8; ++kt){
    const float* gx = x + (size_t)(t0 + arow) * 256 + kt * 32 + acg * 8;
    float4 v0 = *(const float4*)gx;
    float4 v1 = *(const float4*)(gx + 4);
    ushort4 h0, h1, l0, l1;
    h0.x = f2bf(v0.x); h0.y = f2bf(v0.y); h0.z = f2bf(v0.z); h0.w = f2bf(v0.w);
    h1.x = f2bf(v1.x); h1.y = f2bf(v1.y); h1.z = f2bf(v1.z); h1.w = f2bf(v1.w);
    l0.x = f2bf(v0.x - bf2f(h0.x)); l0.y = f2bf(v0.y - bf2f(h0.y));
    l0.z = f2bf(v0.z - bf2f(h0.z)); l0.w = f2bf(v0.w - bf2f(h0.w));
    l1.x = f2bf(v1.x - bf2f(h1.x)); l1.y = f2bf(v1.y - bf2f(h1.y));
    l1.z = f2bf(v1.z - bf2f(h1.z)); l1.w = f2bf(v1.w - bf2f(h1.w));
    u16* gxb = x_bf + (size_t)(t0 + arow) * 256 + kt * 32 + acg * 8;
    *(ushort4*)gxb = h0; *(ushort4*)(gxb + 4) = h1;
    const u16* gwh = w1h + (size_t)brow * 256 + kt * 32 + bhalf * 16;
    const u16* gwl = w1l + (size_t)brow * 256 + kt * 32 + bhalf * 16;
    uint4 wh0 = *(const uint4*)gwh;
    uint4 wh1 = *(const uint4*)(gwh + 8);
    uint4 wl0 = *(const uint4*)gwl;
    uint4 wl1 = *(const uint4*)(gwl + 8);
    __syncthreads();
    *(ushort4*)&Ah[arow*40 + acg*8    ] = h0;
    *(ushort4*)&Ah[arow*40 + acg*8 + 4] = h1;
    *(ushort4*)&Al[arow*40 + acg*8    ] = l0;
    *(ushort4*)&Al[arow*40 + acg*8 + 4] = l1;
    *(uint4*)&Bh[brow*40 + bhalf*16    ] = wh0;
    *(uint4*)&Bh[brow*40 + bhalf*16 + 8] = wh1;
    *(uint4*)&Bl[brow*40 + bhalf*16    ] = wl0;
    *(uint4*)&Bl[brow*40 + bhalf*16 + 8] = wl1;
    __syncthreads();
    short8 ah[4], al[4], bhf[2], blf[2];
    #pragma unroll
    for (int i = 0; i < 4; ++i){
      ah[i] = *(const short8*)&Ah[(i*16 + l16)*40 + quad*8];
      al[i] = *(const short8*)&Al[(i*16 + l16)*40 + quad*8];
    }
    #pragma unroll
    for (int j = 0; j < 2; ++j){
      bhf[j] = *(const short8*)&Bh[(wv*32 + j*16 + l16)*40 + quad*8];
      blf[j] = *(const short8*)&Bl[(wv*32 + j*16 + l16)*40 + quad*8];
    }
    #pragma unroll
    for (int i = 0; i < 4; ++i)
      #pragma unroll
      for (int j = 0; j < 2; ++j){
        acc[i][j] = __builtin_amdgcn_mfma_f32_16x16x32_bf16(ah[i], bhf[j], acc[i][j], 0, 0, 0);
        acc[i][j] = __builtin_amdgcn_mfma_f32_16x16x32_bf16(ah[i], blf[j], acc[i][j], 0, 0, 0);
        acc[i][j] = __builtin_amdgcn_mfma_f32_16x16x32_bf16(al[i], bhf[j], acc[i][j], 0, 0, 0);
      }
  }
  __syncthreads();   // all frag reads done before Hs overlay

  #pragma unroll
  for (int i = 0; i < 4; ++i)
    #pragma unroll
    for (int j = 0; j < 2; ++j){
      int col = wv*32 + j*16 + l16;
      float bb = b1[col];
      #pragma unroll
      for (int rr = 0; rr < 4; ++rr){
        float h = acc[i][j][rr] + bb;
        Hs[(i*16 + quad*4 + rr)*132 + col] = h > 0.f ? h : 0.f;
      }
    }
  __syncthreads();

  // logits + softmax: 8 lanes per token (e = tid&7), 32 tokens/pass (fp32)
  #pragma unroll
  for (int pass = 0; pass < 2; ++pass){
    int mtok = (tid >> 3) + pass * 32;
    int e = tid & 7;
    const float4* w2r = (const float4*)(w2 + e * 128);
    float l = b2[e];
    #pragma unroll
    for (int k4 = 0; k4 < 32; ++k4){
      float4 w = w2r[k4];
      int k = k4 * 4;
      l = fmaf(Hs[mtok*132+k  ], w.x, l);
      l = fmaf(Hs[mtok*132+k+1], w.y, l);
      l = fmaf(Hs[mtok*132+k+2], w.z, l);
      l = fmaf(Hs[mtok*132+k+3], w.w, l);
    }
    float mv = l; int mi = e;
    #pragma unroll
    for (int off = 1; off < 8; off <<= 1){
      float ov = __shfl_xor(mv, off, 64);
      int   oi = __shfl_xor(mi, off, 64);
      if (ov > mv || (ov == mv && oi < mi)){ mv = ov; mi = oi; }
    }
    float sum = expf(l - mv);
    #pragma unroll
    for (int off = 1; off < 8; off <<= 1) sum += __shfl_xor(sum, off, 64);
    if (e == 0){
      int t = t0 + mtok;
      routes[t] = mi;
      pmax[t] = 1.0f / sum;
      atomicAdd(&lhist[mi], 1);
    }
  }
  __syncthreads();
  if (tid < 8 && lhist[tid] > 0) atomicAdd(&counts[tid], lhist[tid]);
}

// ---------------- counting-sort machinery ----------------
__global__ void k_offsets(const int* __restrict__ counts, int* __restrict__ offs,
                          int* __restrict__ sorted){
  __shared__ int so[9];
  if (threadIdx.x == 0){
    int o = 0; so[0] = 0;
    for (int e = 0; e < 8; ++e){ o += ((counts[e] + 127) >> 7) << 7; so[e+1] = o; }
    for (int e = 0; e < 9; ++e) offs[e] = so[e];
  }
  __syncthreads();
  for (int e = 0; e < 8; ++e){
    int s = so[e] + counts[e], en = so[e+1];
    for (int i = s + (int)threadIdx.x; i < en; i += (int)blockDim.x) sorted[i] = -1;
  }
}

// Block-aggregated scatter; also emits rank[t] = sorted position (for k_attn's
// sorted-order output, so the proj GEMM reads a contiguous A).
__global__ __launch_bounds__(256) void k_scatter(
    const int* __restrict__ routes, const int* __restrict__ offs,
    int* __restrict__ cursors, int* __restrict__ sorted, int* __restrict__ rank)
{
  __shared__ int lc[8], lb[8];
  int tid = threadIdx.x;
  int t = blockIdx.x * 256 + tid;
  if (tid < 8) lc[tid] = 0;
  __syncthreads();
  int e = routes[t];
  int rl = atomicAdd(&lc[e], 1);             // LDS atomic
  __syncthreads();
  if (tid < 8 && lc[tid] > 0) lb[tid] = atomicAdd(&cursors[tid], lc[tid]);
  __syncthreads();
  int pos = offs[e] + lb[e] + rl;
  sorted[pos] = t;
  rank[t] = pos;
}

// ---------------- gather x into sorted order (zero-fill padding) ----------------
// 16 rows/block; 32 lanes read one 512B token row contiguously -> coalesced.
__global__ __launch_bounds__(256) void k_gather(
    const u16* __restrict__ xbf, const int* __restrict__ sorted,
    const int* __restrict__ offs, u16* __restrict__ xs)
{
  int total = offs[8];
  int tid = threadIdx.x;
  #pragma unroll
  for (int h = 0; h < 2; ++h){
    int cid = tid + h * 256;
    int row = cid >> 5, chunk = cid & 31;
    int gr = blockIdx.x * 16 + row;
    int t = (gr < total) ? sorted[gr] : -1;
    uint4 v = {0u, 0u, 0u, 0u};
    if (t >= 0) v = *(const uint4*)(xbf + (size_t)t * 256 + chunk * 8);
    *(uint4*)(xs + (size_t)gr * 256 + chunk * 8) = v;
  }
}

// ---------------- grouped MoE GEMM: out[t] = A_sorted @ W[e]^T + bias[e] ----------------
// Chunk-based staging (R8): thread (row,chunk) -> full-line transactions.
// B rows permuted so frag j of lane l16 = output col l16*4+j (vectorized epilogue).
// NEW (R9): for the QKV GEMM (!PROJ), the epilogue applies 2D RoPE to Q,K and
// folds SCALE_ATT into Q. Each thread owns 4 consecutive channels = 2 complete
// rotation pairs; a wave's 64-col span is entirely Q, K, or V (no divergence).
// This removes all trig + Q/K LDS staging from the latency-bound attn kernel.
#define ASTR 56   // LDS row stride (elems): 112B, 16B-aligned, 2-way banking
template<int NOUT, bool PROJ>
__global__ __launch_bounds__(256) void k_gemm(
    const u16* __restrict__ A, const u16* __restrict__ W,
    const float* __restrict__ bias, const int* __restrict__ sidx,
    const int* __restrict__ offs, const float* __restrict__ pmax,
    u16* __restrict__ outb, float* __restrict__ outf)
{
  __shared__ __align__(16) u16 As[128 * ASTR];
  __shared__ __align__(16) u16 Bs[128 * ASTR];
  int tid = threadIdx.x;
  int m0 = blockIdx.y * 128;
  int n0 = blockIdx.x * 128;
  int total = offs[8];
  if (m0 >= total) return;
  int e = 0;
  #pragma unroll
  for (int i = 1; i < 8; ++i) if (m0 >= offs[i]) e = i;

  int wv = tid >> 6, lane = tid & 63, quad = lane >> 4, l16 = lane & 15;
  int wrow = (wv >> 1) * 64, wcol = (wv & 1) * 64;

  // chunk staging: thread handles (row0, c0) and (row0+64, c0); 16B each
  int row0 = tid >> 2, c0 = tid & 3;
  const u16* aptr0 = A + (size_t)(m0 + row0) * 256 + c0 * 8;
  const u16* aptr1 = aptr0 + (size_t)64 * 256;
  int pc = (row0 >> 4) + (row0 & 15) * 4;          // permuted col within 64-half
  const u16* bptr0 = W + ((size_t)e * NOUT + n0 + pc) * 256 + c0 * 8;
  const u16* bptr1 = W + ((size_t)e * NOUT + n0 + 64 + pc) * 256 + c0 * 8;

  f32x4 acc[4][4];
  #pragma unroll
  for (int i = 0; i < 4; ++i)
    #pragma unroll
    for (int j = 0; j < 4; ++j)
      #pragma unroll
      for (int r = 0; r < 4; ++r) acc[i][j][r] = 0.f;

  // prologue: prefetch k-tile 0
  uint4 a0 = *(const uint4*)aptr0, a1 = *(const uint4*)aptr1;
  uint4 b0 = *(const uint4*)bptr0, b1 = *(const uint4*)bptr1;

  for (int kt = 0; kt < 8; ++kt){
    __syncthreads();
    *(uint4*)&As[ row0      *ASTR + c0*8] = a0;
    *(uint4*)&As[(row0 + 64)*ASTR + c0*8] = a1;
    *(uint4*)&Bs[ row0      *ASTR + c0*8] = b0;
    *(uint4*)&Bs[(row0 + 64)*ASTR + c0*8] = b1;
    __syncthreads();
    if (kt < 7){                       // prefetch kt+1; overlaps frag reads + MFMA
      a0 = *(const uint4*)(aptr0 + (kt+1)*32);
      a1 = *(const uint4*)(aptr1 + (kt+1)*32);
      b0 = *(const uint4*)(bptr0 + (kt+1)*32);
      b1 = *(const uint4*)(bptr1 + (kt+1)*32);
    }
    short8 af[4], bfv[4];
    #pragma unroll
    for (int i = 0; i < 4; ++i)
      af[i] = *(const short8*)&As[(wrow + i*16 + l16)*ASTR + quad*8];
    #pragma unroll
    for (int j = 0; j < 4; ++j)
      bfv[j] = *(const short8*)&Bs[(wcol + j*16 + l16)*ASTR + quad*8];
    #pragma unroll
    for (int i = 0; i < 4; ++i)
      #pragma unroll
      for (int j = 0; j < 4; ++j)
        acc[i][j] = __builtin_amdgcn_mfma_f32_16x16x32_bf16(af[i], bfv[j], acc[i][j], 0, 0, 0);
  }

  // epilogue: frag j of lane l16 = output col n0+wcol+l16*4+j (contiguous)
  float4 bj4 = *(const float4*)&bias[e*NOUT + n0 + wcol + l16*4];
  if (PROJ){
    #pragma unroll
    for (int i = 0; i < 4; ++i){
      #pragma unroll
      for (int ri = 0; ri < 4; ++ri){
        int row = wrow + i*16 + quad*4 + ri;        // C/D: row=quad*4+reg [m89]
        int t = sidx[m0 + row];
        if (t < 0) continue;
        float pm = pmax[t];
        float4 ov;
        ov.x = (acc[i][0][ri] + bj4.x) * pm;
        ov.y = (acc[i][1][ri] + bj4.y) * pm;
        ov.z = (acc[i][2][ri] + bj4.z) * pm;
        ov.w = (acc[i][3][ri] + bj4.w) * pm;
        *(float4*)&outf[(size_t)t * NOUT + n0 + wcol + l16*4] = ov;
      }
    }
  } else {
    // qkv: cols [0,256)=Q (rotate + scale), [256,512)=K (rotate), [512,768)=V
    int col0 = n0 + wcol + l16*4;
    bool isqk = (col0 < 512);
    float inv0 = 0.f, inv1 = 0.f;
    float qsc = (col0 < 256) ? SCALE_ATT : 1.0f;
    if (isqk){
      int p0 = (col0 & 15) >> 1;                    // pair idx within half: 0,2,4,6
      inv0 = __expf(-1.1512925465f * (float)p0);    // 10000^(-p0/8)
      inv1 = inv0 * 0.31622776601683794f;           // * 10^-0.5 -> 10000^(-(p0+1)/8)
    }
    #pragma unroll
    for (int i = 0; i < 4; ++i){
      #pragma unroll
      for (int ri = 0; ri < 4; ++ri){
        int row = wrow + i*16 + quad*4 + ri;
        int t = sidx[m0 + row];
        if (t < 0) continue;
        float vx = acc[i][0][ri] + bj4.x;
        float vy = acc[i][1][ri] + bj4.y;
        float vz = acc[i][2][ri] + bj4.z;
        float vw = acc[i][3][ri] + bj4.w;
        if (isqk){
          // token window coords: r=(t>>6)&7 (row half), c=t&7 (col half)
          float pos = (float)((col0 & 16) ? (t & 7) : ((t >> 6) & 7));
          float a0 = pos * inv0, a1 = pos * inv1;
          float s0, c0s, s1, c1s;
          __sincosf(a0, &s0, &c0s);
          __sincosf(a1, &s1, &c1s);
          float r0 = (vx*c0s - vy*s0) * qsc;
          float r1 = (vx*s0 + vy*c0s) * qsc;
          float r2 = (vz*c1s - vw*s1) * qsc;
          float r3 = (vz*s1 + vw*c1s) * qsc;
          vx = r0; vy = r1; vz = r2; vw = r3;
        }
        uint2 ov;
        ov.x = (u32)f2bf(vx) | ((u32)f2bf(vy) << 16);
        ov.y = (u32)f2bf(vz) | ((u32)f2bf(vw) << 16);
        *(uint2*)&outb[(size_t)t * NOUT + n0 + wcol + l16*4] = ov;
      }
    }
  }
}

// ---------------- MFMA windowed attention (RoPE pre-applied in QKV GEMM) ----------------
// One 64-thread block per (window, head). Q,K loaded straight from global in
// MFMA fragment layout (pre-rotated, Q pre-scaled) -> no Q/K LDS staging, no
// trig on the latency path. Row-sums via shfl_xor (ones-MFMA trick removed).
// LDS/block = Ps 9216B + Vt 4608B = 13824B -> 11 blocks/CU (was 8 waves/CU).
__global__ __launch_bounds__(64, 3) void k_attn(const u16* __restrict__ qkv,
                                                const int* __restrict__ rank,
                                                u16* __restrict__ attn_s)
{
  __shared__ __align__(16) u16 Ps[64*72];   // P bf16, permuted cols, stride 72
  __shared__ __align__(16) u16 Vt[32*72];   // V^T: Vt[d][pi(n)]

  int lane = threadIdx.x;
  int quad = lane >> 4, l16 = lane & 15;
  int wh = blockIdx.x;                       // 0..4095 (window*8 + head)
  int win = wh >> 3, head = wh & 7;
  int b = win >> 6, wy = (win >> 3) & 7, wx = win & 7;
  int tb = b*4096 + wy*512 + wx*8;           // token(n) = tb + (n>>3)*64 + (n&7)

  // Q/K fragments direct from global: frag i, lane (quad,l16) = token i*16+l16,
  // channels head*32 + quad*8 .. +7 (16B, aligned)
  short8 qf[4], kf[4];
  #pragma unroll
  for (int i = 0; i < 4; ++i){
    int n = i*16 + l16;
    const u16* p = qkv + (size_t)(tb + (n>>3)*64 + (n&7)) * 768 + head*32 + quad*8;
    qf[i] = *(const short8*)p;
    kf[i] = *(const short8*)(p + 256);
  }
  // V row for this lane's token (issued early; staged after QK compute)
  int tn = tb + (lane>>3)*64 + (lane&7);
  const uint4* vb = (const uint4*)(qkv + (size_t)tn * 768 + 512 + head*32);
  uint4 va[4];
  #pragma unroll
  for (int i = 0; i < 4; ++i) va[i] = vb[i];

  // S = Q K^T (scale already folded into Q)
  f32x4 sa[4][4];
  #pragma unroll
  for (int i = 0; i < 4; ++i)
    #pragma unroll
    for (int j = 0; j < 4; ++j){
      #pragma unroll
      for (int rr = 0; rr < 4; ++rr) sa[i][j][rr] = 0.f;
      sa[i][j] = __builtin_amdgcn_mfma_f32_16x16x32_bf16(qf[i], kf[j], sa[i][j], 0, 0, 0);
    }

  // P = exp(S) -> bf16 -> Ps (permuted col pi(n) = (n&15)*4 + (n>>4));
  // row-sum accumulated per (i,rr) then shfl-reduced over l16 (cols).
  f32x4 rs[4];
  #pragma unroll
  for (int i = 0; i < 4; ++i)
    #pragma unroll
    for (int rr = 0; rr < 4; ++rr){
      float e0 = __expf(sa[i][0][rr]);
      float e1 = __expf(sa[i][1][rr]);
      float e2 = __expf(sa[i][2][rr]);
      float e3 = __expf(sa[i][3][rr]);
      rs[i][rr] = (e0 + e1) + (e2 + e3);
      uint2 pk;
      pk.x = (u32)f2bf(e0) | ((u32)f2bf(e1) << 16);
      pk.y = (u32)f2bf(e2) | ((u32)f2bf(e3) << 16);
      *(uint2*)&Ps[(i*16 + quad*4 + rr)*72 + l16*4] = pk;
    }
  #pragma unroll
  for (int i = 0; i < 4; ++i)
    #pragma unroll
    for (int rr = 0; rr < 4; ++rr){
      #pragma unroll
      for (int off = 1; off < 16; off <<= 1)
        rs[i][rr] += __shfl_xor(rs[i][rr], off, 64);
    }

  // stage V transposed+permuted: Vt[d][pi(n)] = V[n][d]
  u32* vu = (u32*)va;
  int pn = l16 * 4 + quad;                   // pi(lane)
  #pragma unroll
  for (int d2 = 0; d2 < 16; ++d2){
    Vt[(2*d2  )*72 + pn] = (u16)(vu[d2] & 0xffff);
    Vt[(2*d2+1)*72 + pn] = (u16)(vu[d2] >> 16);
  }

  // PV: P A-frags from Ps, V B-frags from Vt (both in pi-space), 2 k-steps of 32.
  f32x4 oa[4][2];
  #pragma unroll
  for (int i = 0; i < 4; ++i)
    #pragma unroll
    for (int rr = 0; rr < 4; ++rr){ oa[i][0][rr] = 0.f; oa[i][1][rr] = 0.f; }
  #pragma unroll
  for (int ks = 0; ks < 2; ++ks){
    short8 vf0 = *(const short8*)&Vt[(     l16)*72 + ks*32 + quad*8];
    short8 vf1 = *(const short8*)&Vt[(16 + l16)*72 + ks*32 + quad*8];
    #pragma unroll
    for (int i = 0; i < 4; ++i){
      short8 pf = *(const short8*)&Ps[(i*16 + l16)*72 + ks*32 + quad*8];
      oa[i][0] = __builtin_amdgcn_mfma_f32_16x16x32_bf16(pf, vf0, oa[i][0], 0, 0, 0);
      oa[i][1] = __builtin_amdgcn_mfma_f32_16x16x32_bf16(pf, vf1, oa[i][1], 0, 0, 0);
    }
  }

  // epilogue: O[m][d] = oa/rowsum; store bf16 at sorted position rank[token]
  #pragma unroll
  for (int i = 0; i < 4; ++i)
    #pragma unroll
    for (int rr = 0; rr < 4; ++rr){
      float inv = __builtin_amdgcn_rcpf(rs[i][rr]);
      int m = i*16 + quad*4 + rr;
      int tm = tb + (m >> 3) * 64 + (m & 7);
      int pos = rank[tm];
      u16* op = attn_s + (size_t)pos * 256 + head * 32 + l16;
      op[0]  = f2bf(oa[i][0][rr] * inv);
      op[16] = f2bf(oa[i][1][rr] * inv);
    }
}

// ---------------- launch ----------------
extern "C" void kernel_launch(void* const* d_in, const int* in_sizes, int n_in,
                              void* d_out, int out_size, void* d_ws, size_t ws_size,
                              hipStream_t stream){
  const float* x     = (const float*)d_in[0];
  const float* rw1   = (const float*)d_in[1];
  const float* rb1   = (const float*)d_in[2];
  const float* rw2   = (const float*)d_in[3];
  const float* rb2   = (const float*)d_in[4];
  const float* qkvw  = (const float*)d_in[5];
  const float* qkvb  = (const float*)d_in[6];
  const float* projw = (const float*)d_in[7];
  const float* projb = (const float*)d_in[8];
  float* out = (float*)d_out;

  char* ws = (char*)d_ws;
  u16*   x_bf    = (u16*)(ws);                       // 16,777,216 B
  u16*   qkv_bf  = (u16*)(ws + 16777216);            // 50,331,648 B
  // shared region (disjoint lifetimes): w1 split (router) -> xs (qkv gemm)
  // -> attn_s (attn + proj gemm). 17,301,504 B (33792 rows x 512B).
  u16*   w1h     = (u16*)(ws + 67108864);
  u16*   w1l     = w1h + 32768;
  u16*   xs      = (u16*)(ws + 67108864);
  u16*   attn_s  = (u16*)(ws + 67108864);
  u16*   qw_bf   = (u16*)(ws + 84410368);            //  3,145,728 B
  u16*   pw_bf   = (u16*)(ws + 87556096);            //  1,048,576 B
  int*   routes  = (int*)(ws + 88604672);            //    131,072 B
  float* pmaxp   = (float*)(ws + 88735744);          //    131,072 B
  int*   sorted  = (int*)(ws + 88866816);            //    135,168 B (33792 slots)
  int*   rank    = (int*)(ws + 89001984);            //    131,072 B
  int*   counts  = (int*)(ws + 89133056);
  int*   cursors = (int*)(ws + 89133056 + 32);
  int*   offs    = (int*)(ws + 89133056 + 64);

  k_init<<<1, 64, 0, stream>>>(counts, cursors);
  k_cvt<<<1536, 256, 0, stream>>>(qkvw,  qw_bf, 1572864/4);
  k_cvt<<< 512, 256, 0, stream>>>(projw, pw_bf,  524288/4);
  k_cvt_split<<<128, 256, 0, stream>>>(rw1, w1h, w1l, 32768);
  k_router<<<512, 256, 0, stream>>>(x, w1h, w1l, rb1, rw2, rb2, routes, pmaxp, counts, x_bf);
  k_offsets<<<1, 256, 0, stream>>>(counts, offs, sorted);
  k_scatter<<<128, 256, 0, stream>>>(routes, offs, cursors, sorted, rank);
  k_gather<<<2112, 256, 0, stream>>>(x_bf, sorted, offs, xs);   // overwrites w1 split (dead)
  k_gemm<768, false><<<dim3(6, 264), 256, 0, stream>>>(xs, qw_bf, qkvb, sorted, offs,
                                                       nullptr, qkv_bf, nullptr);
  k_attn<<<4096, 64, 0, stream>>>(qkv_bf, rank, attn_s);        // overwrites xs (dead)
  k_gemm<256, true><<<dim3(2, 264), 256, 0, stream>>>(attn_s, pw_bf, projb, sorted, offs,
                                                      pmaxp, nullptr, out);
}

// Round 2
// 197.356 us; speedup vs baseline: 1.1385x; 1.1382x over previous
//
#include <hip/hip_runtime.h>
#include <hip/hip_bf16.h>

typedef unsigned short u16;
typedef unsigned int u32;
typedef __attribute__((ext_vector_type(8))) short short8;   // 8 bf16 (4 VGPRs) MFMA operand
typedef __attribute__((ext_vector_type(4))) float f32x4;    // MFMA 16x16 accumulator

#define T_TOK 32768
#define SCALE_ATT 0.17677669529663687f   // 32^-0.5

__device__ __forceinline__ u16 f2bf(float f){
  u32 u = __float_as_uint(f);
  u32 r = u + 0x7fffu + ((u >> 16) & 1u);   // RTN-even
  return (u16)(r >> 16);
}
__device__ __forceinline__ float bf2f(u16 h){
  return __uint_as_float(((u32)h) << 16);
}

// XCD-chunked bijective block swizzle (nwg % 8 == 0): consecutive logical
// blocks land on the SAME XCD so shared operand panels hit its private L2.
__device__ __forceinline__ int xcd_swz(int flat, int nwg){
  return (flat & 7) * (nwg >> 3) + (flat >> 3);
}

// ---------------- fused prep: weight cvt + w1 split + sorted/-counts init ----
// b<1536: qkvw cvt | <2048: projw cvt | <2176: rw1 split | <2209: sorted=-1 | last: counters
__global__ __launch_bounds__(256) void k_prep(
    const float* __restrict__ qkvw, u16* __restrict__ qw_bf,
    const float* __restrict__ projw, u16* __restrict__ pw_bf,
    const float* __restrict__ rw1, u16* __restrict__ w1h, u16* __restrict__ w1l,
    int* __restrict__ sorted, int* __restrict__ counts, int* __restrict__ cursors)
{
  int b = blockIdx.x, tid = threadIdx.x;
  if (b < 1536){
    int i = b * 256 + tid;                       // < 393216 float4
    float4 v = ((const float4*)qkvw)[i];
    ushort4 o;
    o.x = f2bf(v.x); o.y = f2bf(v.y); o.z = f2bf(v.z); o.w = f2bf(v.w);
    ((ushort4*)qw_bf)[i] = o;
  } else if (b < 2048){
    int i = (b - 1536) * 256 + tid;              // < 131072 float4
    float4 v = ((const float4*)projw)[i];
    ushort4 o;
    o.x = f2bf(v.x); o.y = f2bf(v.y); o.z = f2bf(v.z); o.w = f2bf(v.w);
    ((ushort4*)pw_bf)[i] = o;
  } else if (b < 2176){
    int i = (b - 2048) * 256 + tid;              // < 32768
    float v = rw1[i];
    u16 h = f2bf(v);
    w1h[i] = h;
    w1l[i] = f2bf(v - bf2f(h));                  // exact residual in fp32
  } else if (b < 2209){
    int i = (b - 2176) * 256 + tid;              // < 8448 int4 = 33792 ints
    int4 m1 = {-1, -1, -1, -1};
    ((int4*)sorted)[i] = m1;
  } else {
    if (tid < 8){ counts[tid] = 0; cursors[tid] = 0; }
  }
}

// ---------------- MFMA router (split-bf16 "bf16x3") ----------------
// h = relu(x@w1^T+b1) via MFMA: x=x_hi+x_lo, w1=w1_hi+w1_lo (bf16 pairs);
// h ~ hi*hi + hi*lo + lo*hi in fp32 accum -> logit err ~1e-6 << top-2 gap.
__global__ __launch_bounds__(256) void k_router(
    const float* __restrict__ x, const u16* __restrict__ w1h, const u16* __restrict__ w1l,
    const float* __restrict__ b1, const float* __restrict__ w2, const float* __restrict__ b2,
    int* __restrict__ routes, float* __restrict__ pmax, int* __restrict__ counts,
    u16* __restrict__ x_bf)
{
  __shared__ __align__(16) char smem[64*132*4];   // 33792 B
  u16* Ah = (u16*)smem;          // 64 x 40
  u16* Al = Ah + 2560;           // 64 x 40
  u16* Bh = Al + 2560;           // 128 x 40
  u16* Bl = Bh + 5120;           // 128 x 40
  float* Hs = (float*)smem;      // overlay after MFMA: 64 x 132
  __shared__ int lhist[8];

  int tid = threadIdx.x;
  int t0 = blockIdx.x * 64;
  int wv = tid >> 6, lane = tid & 63, quad = lane >> 4, l16 = lane & 15;
  if (tid < 8) lhist[tid] = 0;

  int arow = tid >> 2, acg = tid & 3;        // A staging: 64 rows x 4 col-groups of 8
  int brow = tid >> 1, bhalf = tid & 1;      // B staging: 128 rows x 2 halves of 16

  f32x4 acc[4][2];
  #pragma unroll
  for (int i = 0; i < 4; ++i)
    #pragma unroll
    for (int j = 0; j < 2; ++j)
      #pragma unroll
      for (int rr = 0; rr < 4; ++rr) acc[i][j][rr] = 0.f;

  for (int kt = 0; kt < 8; ++kt){
    const float* gx = x + (size_t)(t0 + arow) * 256 + kt * 32 + acg * 8;
    float4 v0 = *(const float4*)gx;
    float4 v1 = *(const float4*)(gx + 4);
    ushort4 h0, h1, l0, l1;
    h0.x = f2bf(v0.x); h0.y = f2bf(v0.y); h0.z = f2bf(v0.z); h0.w = f2bf(v0.w);
    h1.x = f2bf(v1.x); h1.y = f2bf(v1.y); h1.z = f2bf(v1.z); h1.w = f2bf(v1.w);
    l0.x = f2bf(v0.x - bf2f(h0.x)); l0.y = f2bf(v0.y - bf2f(h0.y));
    l0.z = f2bf(v0.z - bf2f(h0.z)); l0.w = f2bf(v0.w - bf2f(h0.w));
    l1.x = f2bf(v1.x - bf2f(h1.x)); l1.y = f2bf(v1.y - bf2f(h1.y));
    l1.z = f2bf(v1.z - bf2f(h1.z)); l1.w = f2bf(v1.w - bf2f(h1.w));
    u16* gxb = x_bf + (size_t)(t0 + arow) * 256 + kt * 32 + acg * 8;
    *(ushort4*)gxb = h0; *(ushort4*)(gxb + 4) = h1;
    const u16* gwh = w1h + (size_t)brow * 256 + kt * 32 + bhalf * 16;
    const u16* gwl = w1l + (size_t)brow * 256 + kt * 32 + bhalf * 16;
    uint4 wh0 = *(const uint4*)gwh;
    uint4 wh1 = *(const uint4*)(gwh + 8);
    uint4 wl0 = *(const uint4*)gwl;
    uint4 wl1 = *(const uint4*)(gwl + 8);
    __syncthreads();
    *(ushort4*)&Ah[arow*40 + acg*8    ] = h0;
    *(ushort4*)&Ah[arow*40 + acg*8 + 4] = h1;
    *(ushort4*)&Al[arow*40 + acg*8    ] = l0;
    *(ushort4*)&Al[arow*40 + acg*8 + 4] = l1;
    *(uint4*)&Bh[brow*40 + bhalf*16    ] = wh0;
    *(uint4*)&Bh[brow*40 + bhalf*16 + 8] = wh1;
    *(uint4*)&Bl[brow*40 + bhalf*16    ] = wl0;
    *(uint4*)&Bl[brow*40 + bhalf*16 + 8] = wl1;
    __syncthreads();
    short8 ah[4], al[4], bhf[2], blf[2];
    #pragma unroll
    for (int i = 0; i < 4; ++i){
      ah[i] = *(const short8*)&Ah[(i*16 + l16)*40 + quad*8];
      al[i] = *(const short8*)&Al[(i*16 + l16)*40 + quad*8];
    }
    #pragma unroll
    for (int j = 0; j < 2; ++j){
      bhf[j] = *(const short8*)&Bh[(wv*32 + j*16 + l16)*40 + quad*8];
      blf[j] = *(const short8*)&Bl[(wv*32 + j*16 + l16)*40 + quad*8];
    }
    #pragma unroll
    for (int i = 0; i < 4; ++i)
      #pragma unroll
      for (int j = 0; j < 2; ++j){
        acc[i][j] = __builtin_amdgcn_mfma_f32_16x16x32_bf16(ah[i], bhf[j], acc[i][j], 0, 0, 0);
        acc[i][j] = __builtin_amdgcn_mfma_f32_16x16x32_bf16(ah[i], blf[j], acc[i][j], 0, 0, 0);
        acc[i][j] = __builtin_amdgcn_mfma_f32_16x16x32_bf16(al[i], bhf[j], acc[i][j], 0, 0, 0);
      }
  }
  __syncthreads();   // all frag reads done before Hs overlay

  #pragma unroll
  for (int i = 0; i < 4; ++i)
    #pragma unroll
    for (int j = 0; j < 2; ++j){
      int col = wv*32 + j*16 + l16;
      float bb = b1[col];
      #pragma unroll
      for (int rr = 0; rr < 4; ++rr){
        float h = acc[i][j][rr] + bb;
        Hs[(i*16 + quad*4 + rr)*132 + col] = h > 0.f ? h : 0.f;
      }
    }
  __syncthreads();

  // logits + softmax: 8 lanes per token (e = tid&7), 32 tokens/pass (fp32)
  #pragma unroll
  for (int pass = 0; pass < 2; ++pass){
    int mtok = (tid >> 3) + pass * 32;
    int e = tid & 7;
    const float4* w2r = (const float4*)(w2 + e * 128);
    float l = b2[e];
    #pragma unroll
    for (int k4 = 0; k4 < 32; ++k4){
      float4 w = w2r[k4];
      int k = k4 * 4;
      l = fmaf(Hs[mtok*132+k  ], w.x, l);
      l = fmaf(Hs[mtok*132+k+1], w.y, l);
      l = fmaf(Hs[mtok*132+k+2], w.z, l);
      l = fmaf(Hs[mtok*132+k+3], w.w, l);
    }
    float mv = l; int mi = e;
    #pragma unroll
    for (int off = 1; off < 8; off <<= 1){
      float ov = __shfl_xor(mv, off, 64);
      int   oi = __shfl_xor(mi, off, 64);
      if (ov > mv || (ov == mv && oi < mi)){ mv = ov; mi = oi; }
    }
    float sum = expf(l - mv);
    #pragma unroll
    for (int off = 1; off < 8; off <<= 1) sum += __shfl_xor(sum, off, 64);
    if (e == 0){
      int t = t0 + mtok;
      routes[t] = mi;
      pmax[t] = 1.0f / sum;
      atomicAdd(&lhist[mi], 1);
    }
  }
  __syncthreads();
  if (tid < 8 && lhist[tid] > 0) atomicAdd(&counts[tid], lhist[tid]);
}

// ---------------- scatter (offsets fused: every block recomputes the 8-entry
// prefix from counts; block 0 publishes offs). sorted pre-filled -1 by k_prep.
__global__ __launch_bounds__(256) void k_scatter(
    const int* __restrict__ routes, const int* __restrict__ counts,
    int* __restrict__ cursors, int* __restrict__ sorted, int* __restrict__ rank,
    int* __restrict__ offs)
{
  __shared__ int lc[8], lb[8], so[9];
  int tid = threadIdx.x;
  if (tid == 0){
    int o = 0; so[0] = 0;
    #pragma unroll
    for (int e = 0; e < 8; ++e){ o += ((counts[e] + 127) >> 7) << 7; so[e+1] = o; }
  }
  if (tid < 8) lc[tid] = 0;
  __syncthreads();
  int t = blockIdx.x * 256 + tid;
  int e = routes[t];
  int rl = atomicAdd(&lc[e], 1);             // LDS atomic
  __syncthreads();
  if (tid < 8 && lc[tid] > 0) lb[tid] = atomicAdd(&cursors[tid], lc[tid]);
  __syncthreads();
  int pos = so[e] + lb[e] + rl;
  sorted[pos] = t;
  rank[t] = pos;
  if (blockIdx.x == 0 && tid < 9) offs[tid] = so[tid];
}

// ---------------- grouped MoE GEMM: out[t] = A_sorted @ W[e]^T + bias[e] ----------------
// Chunk staging (R8) + XCD-chunked swizzle (R10): the NB col-blocks of one
// row-panel run on the SAME XCD -> A panel fetched once, reused from L2.
// For !PROJ, A is read DIRECTLY in token order via sorted[] indirection
// (k_gather deleted): 4 lanes cover one 64B row-slice; padded rows clamp to
// token 0 (finite garbage, epilogue skips t<0). Epilogue (!PROJ) applies 2D
// RoPE to Q,K and folds SCALE_ATT into Q (R9).
#define ASTR 56   // LDS row stride (elems): 112B, 16B-aligned, 2-way banking
template<int NOUT, bool PROJ, int NB, int NWG>
__global__ __launch_bounds__(256) void k_gemm(
    const u16* __restrict__ A, const u16* __restrict__ W,
    const float* __restrict__ bias, const int* __restrict__ sidx,
    const int* __restrict__ offs, const float* __restrict__ pmax,
    u16* __restrict__ outb, float* __restrict__ outf)
{
  __shared__ __align__(16) u16 As[128 * ASTR];
  __shared__ __align__(16) u16 Bs[128 * ASTR];
  int tid = threadIdx.x;
  int flat = blockIdx.y * NB + blockIdx.x;     // hw dispatch order (x fastest)
  int logical = xcd_swz(flat, NWG);
  int m0 = (logical / NB) * 128;
  int n0 = (logical % NB) * 128;
  int total = offs[8];
  if (m0 >= total) return;
  int e = 0;
  #pragma unroll
  for (int i = 1; i < 8; ++i) if (m0 >= offs[i]) e = i;

  int wv = tid >> 6, lane = tid & 63, quad = lane >> 4, l16 = lane & 15;
  int wrow = (wv >> 1) * 64, wcol = (wv & 1) * 64;

  // chunk staging: thread handles (row0, c0) and (row0+64, c0); 16B each
  int row0 = tid >> 2, c0 = tid & 3;
  const u16 *aptr0, *aptr1;
  if (PROJ){
    aptr0 = A + (size_t)(m0 + row0) * 256 + c0 * 8;
    aptr1 = aptr0 + (size_t)64 * 256;
  } else {
    int tA0 = sidx[m0 + row0];      if (tA0 < 0) tA0 = 0;   // clamp: row discarded in epilogue
    int tA1 = sidx[m0 + row0 + 64]; if (tA1 < 0) tA1 = 0;
    aptr0 = A + (size_t)tA0 * 256 + c0 * 8;
    aptr1 = A + (size_t)tA1 * 256 + c0 * 8;
  }
  int pc = (row0 >> 4) + (row0 & 15) * 4;          // permuted col within 64-half
  const u16* bptr0 = W + ((size_t)e * NOUT + n0 + pc) * 256 + c0 * 8;
  const u16* bptr1 = W + ((size_t)e * NOUT + n0 + 64 + pc) * 256 + c0 * 8;

  f32x4 acc[4][4];
  #pragma unroll
  for (int i = 0; i < 4; ++i)
    #pragma unroll
    for (int j = 0; j < 4; ++j)
      #pragma unroll
      for (int r = 0; r < 4; ++r) acc[i][j][r] = 0.f;

  // prologue: prefetch k-tile 0
  uint4 a0 = *(const uint4*)aptr0, a1 = *(const uint4*)aptr1;
  uint4 b0 = *(const uint4*)bptr0, b1 = *(const uint4*)bptr1;

  for (int kt = 0; kt < 8; ++kt){
    __syncthreads();
    *(uint4*)&As[ row0      *ASTR + c0*8] = a0;
    *(uint4*)&As[(row0 + 64)*ASTR + c0*8] = a1;
    *(uint4*)&Bs[ row0      *ASTR + c0*8] = b0;
    *(uint4*)&Bs[(row0 + 64)*ASTR + c0*8] = b1;
    __syncthreads();
    if (kt < 7){                       // prefetch kt+1; overlaps frag reads + MFMA
      a0 = *(const uint4*)(aptr0 + (kt+1)*32);
      a1 = *(const uint4*)(aptr1 + (kt+1)*32);
      b0 = *(const uint4*)(bptr0 + (kt+1)*32);
      b1 = *(const uint4*)(bptr1 + (kt+1)*32);
    }
    short8 af[4], bfv[4];
    #pragma unroll
    for (int i = 0; i < 4; ++i)
      af[i] = *(const short8*)&As[(wrow + i*16 + l16)*ASTR + quad*8];
    #pragma unroll
    for (int j = 0; j < 4; ++j)
      bfv[j] = *(const short8*)&Bs[(wcol + j*16 + l16)*ASTR + quad*8];
    #pragma unroll
    for (int i = 0; i < 4; ++i)
      #pragma unroll
      for (int j = 0; j < 4; ++j)
        acc[i][j] = __builtin_amdgcn_mfma_f32_16x16x32_bf16(af[i], bfv[j], acc[i][j], 0, 0, 0);
  }

  // epilogue: frag j of lane l16 = output col n0+wcol+l16*4+j (contiguous)
  float4 bj4 = *(const float4*)&bias[e*NOUT + n0 + wcol + l16*4];
  if (PROJ){
    #pragma unroll
    for (int i = 0; i < 4; ++i){
      #pragma unroll
      for (int ri = 0; ri < 4; ++ri){
        int row = wrow + i*16 + quad*4 + ri;        // C/D: row=quad*4+reg [m89]
        int t = sidx[m0 + row];
        if (t < 0) continue;
        float pm = pmax[t];
        float4 ov;
        ov.x = (acc[i][0][ri] + bj4.x) * pm;
        ov.y = (acc[i][1][ri] + bj4.y) * pm;
        ov.z = (acc[i][2][ri] + bj4.z) * pm;
        ov.w = (acc[i][3][ri] + bj4.w) * pm;
        *(float4*)&outf[(size_t)t * NOUT + n0 + wcol + l16*4] = ov;
      }
    }
  } else {
    // qkv: cols [0,256)=Q (rotate + scale), [256,512)=K (rotate), [512,768)=V
    int col0 = n0 + wcol + l16*4;
    bool isqk = (col0 < 512);
    float inv0 = 0.f, inv1 = 0.f;
    float qsc = (col0 < 256) ? SCALE_ATT : 1.0f;
    if (isqk){
      int p0 = (col0 & 15) >> 1;                    // pair idx within half: 0,2,4,6
      inv0 = __expf(-1.1512925465f * (float)p0);    // 10000^(-p0/8)
      inv1 = inv0 * 0.31622776601683794f;           // * 10^-0.5 -> 10000^(-(p0+1)/8)
    }
    #pragma unroll
    for (int i = 0; i < 4; ++i){
      #pragma unroll
      for (int ri = 0; ri < 4; ++ri){
        int row = wrow + i*16 + quad*4 + ri;
        int t = sidx[m0 + row];
        if (t < 0) continue;
        float vx = acc[i][0][ri] + bj4.x;
        float vy = acc[i][1][ri] + bj4.y;
        float vz = acc[i][2][ri] + bj4.z;
        float vw = acc[i][3][ri] + bj4.w;
        if (isqk){
          // token window coords: r=(t>>6)&7 (row half), c=t&7 (col half)
          float pos = (float)((col0 & 16) ? (t & 7) : ((t >> 6) & 7));
          float a0r = pos * inv0, a1r = pos * inv1;
          float s0, c0s, s1, c1s;
          __sincosf(a0r, &s0, &c0s);
          __sincosf(a1r, &s1, &c1s);
          float r0 = (vx*c0s - vy*s0) * qsc;
          float r1 = (vx*s0 + vy*c0s) * qsc;
          float r2 = (vz*c1s - vw*s1) * qsc;
          float r3 = (vz*s1 + vw*c1s) * qsc;
          vx = r0; vy = r1; vz = r2; vw = r3;
        }
        uint2 ov;
        ov.x = (u32)f2bf(vx) | ((u32)f2bf(vy) << 16);
        ov.y = (u32)f2bf(vz) | ((u32)f2bf(vw) << 16);
        *(uint2*)&outb[(size_t)t * NOUT + n0 + wcol + l16*4] = ov;
      }
    }
  }
}

// ---------------- MFMA windowed attention (RoPE pre-applied in QKV GEMM) ----------------
// One 64-thread block per (window, head), XCD-swizzled so the 8 heads of a
// window (sharing 24KB of qkv) run on the same XCD. Q,K loaded straight from
// global in MFMA fragment layout; row-sums via shfl_xor.
__global__ __launch_bounds__(64, 3) void k_attn(const u16* __restrict__ qkv,
                                                const int* __restrict__ rank,
                                                u16* __restrict__ attn_s)
{
  __shared__ __align__(16) u16 Ps[64*72];   // P bf16, permuted cols, stride 72
  __shared__ __align__(16) u16 Vt[32*72];   // V^T: Vt[d][pi(n)]

  int lane = threadIdx.x;
  int quad = lane >> 4, l16 = lane & 15;
  int wh = xcd_swz(blockIdx.x, 4096);        // 0..4095 (window*8 + head)
  int win = wh >> 3, head = wh & 7;
  int b = win >> 6, wy = (win >> 3) & 7, wx = win & 7;
  int tb = b*4096 + wy*512 + wx*8;           // token(n) = tb + (n>>3)*64 + (n&7)

  // Q/K fragments direct from global: frag i, lane (quad,l16) = token i*16+l16,
  // channels head*32 + quad*8 .. +7 (16B, aligned)
  short8 qf[4], kf[4];
  #pragma unroll
  for (int i = 0; i < 4; ++i){
    int n = i*16 + l16;
    const u16* p = qkv + (size_t)(tb + (n>>3)*64 + (n&7)) * 768 + head*32 + quad*8;
    qf[i] = *(const short8*)p;
    kf[i] = *(const short8*)(p + 256);
  }
  // V row for this lane's token (issued early; staged after QK compute)
  int tn = tb + (lane>>3)*64 + (lane&7);
  const uint4* vb = (const uint4*)(qkv + (size_t)tn * 768 + 512 + head*32);
  uint4 va[4];
  #pragma unroll
  for (int i = 0; i < 4; ++i) va[i] = vb[i];

  // S = Q K^T (scale already folded into Q)
  f32x4 sa[4][4];
  #pragma unroll
  for (int i = 0; i < 4; ++i)
    #pragma unroll
    for (int j = 0; j < 4; ++j){
      #pragma unroll
      for (int rr = 0; rr < 4; ++rr) sa[i][j][rr] = 0.f;
      sa[i][j] = __builtin_amdgcn_mfma_f32_16x16x32_bf16(qf[i], kf[j], sa[i][j], 0, 0, 0);
    }

  // P = exp(S) -> bf16 -> Ps (permuted col pi(n) = (n&15)*4 + (n>>4));
  // row-sum accumulated per (i,rr) then shfl-reduced over l16 (cols).
  f32x4 rs[4];
  #pragma unroll
  for (int i = 0; i < 4; ++i)
    #pragma unroll
    for (int rr = 0; rr < 4; ++rr){
      float e0 = __expf(sa[i][0][rr]);
      float e1 = __expf(sa[i][1][rr]);
      float e2 = __expf(sa[i][2][rr]);
      float e3 = __expf(sa[i][3][rr]);
      rs[i][rr] = (e0 + e1) + (e2 + e3);
      uint2 pk;
      pk.x = (u32)f2bf(e0) | ((u32)f2bf(e1) << 16);
      pk.y = (u32)f2bf(e2) | ((u32)f2bf(e3) << 16);
      *(uint2*)&Ps[(i*16 + quad*4 + rr)*72 + l16*4] = pk;
    }
  #pragma unroll
  for (int i = 0; i < 4; ++i)
    #pragma unroll
    for (int rr = 0; rr < 4; ++rr){
      #pragma unroll
      for (int off = 1; off < 16; off <<= 1)
        rs[i][rr] += __shfl_xor(rs[i][rr], off, 64);
    }

  // stage V transposed+permuted: Vt[d][pi(n)] = V[n][d]
  u32* vu = (u32*)va;
  int pn = l16 * 4 + quad;                   // pi(lane)
  #pragma unroll
  for (int d2 = 0; d2 < 16; ++d2){
    Vt[(2*d2  )*72 + pn] = (u16)(vu[d2] & 0xffff);
    Vt[(2*d2+1)*72 + pn] = (u16)(vu[d2] >> 16);
  }

  // PV: P A-frags from Ps, V B-frags from Vt (both in pi-space), 2 k-steps of 32.
  f32x4 oa[4][2];
  #pragma unroll
  for (int i = 0; i < 4; ++i)
    #pragma unroll
    for (int rr = 0; rr < 4; ++rr){ oa[i][0][rr] = 0.f; oa[i][1][rr] = 0.f; }
  #pragma unroll
  for (int ks = 0; ks < 2; ++ks){
    short8 vf0 = *(const short8*)&Vt[(     l16)*72 + ks*32 + quad*8];
    short8 vf1 = *(const short8*)&Vt[(16 + l16)*72 + ks*32 + quad*8];
    #pragma unroll
    for (int i = 0; i < 4; ++i){
      short8 pf = *(const short8*)&Ps[(i*16 + l16)*72 + ks*32 + quad*8];
      oa[i][0] = __builtin_amdgcn_mfma_f32_16x16x32_bf16(pf, vf0, oa[i][0], 0, 0, 0);
      oa[i][1] = __builtin_amdgcn_mfma_f32_16x16x32_bf16(pf, vf1, oa[i][1], 0, 0, 0);
    }
  }

  // epilogue: O[m][d] = oa/rowsum; store bf16 at sorted position rank[token]
  #pragma unroll
  for (int i = 0; i < 4; ++i)
    #pragma unroll
    for (int rr = 0; rr < 4; ++rr){
      float inv = __builtin_amdgcn_rcpf(rs[i][rr]);
      int m = i*16 + quad*4 + rr;
      int tm = tb + (m >> 3) * 64 + (m & 7);
      int pos = rank[tm];
      u16* op = attn_s + (size_t)pos * 256 + head * 32 + l16;
      op[0]  = f2bf(oa[i][0][rr] * inv);
      op[16] = f2bf(oa[i][1][rr] * inv);
    }
}

// ---------------- launch ----------------
extern "C" void kernel_launch(void* const* d_in, const int* in_sizes, int n_in,
                              void* d_out, int out_size, void* d_ws, size_t ws_size,
                              hipStream_t stream){
  const float* x     = (const float*)d_in[0];
  const float* rw1   = (const float*)d_in[1];
  const float* rb1   = (const float*)d_in[2];
  const float* rw2   = (const float*)d_in[3];
  const float* rb2   = (const float*)d_in[4];
  const float* qkvw  = (const float*)d_in[5];
  const float* qkvb  = (const float*)d_in[6];
  const float* projw = (const float*)d_in[7];
  const float* projb = (const float*)d_in[8];
  float* out = (float*)d_out;

  char* ws = (char*)d_ws;
  u16*   x_bf    = (u16*)(ws);                       // 16,777,216 B
  u16*   qkv_bf  = (u16*)(ws + 16777216);            // 50,331,648 B
  // shared region (disjoint lifetimes): w1 split (router) -> attn_s (attn +
  // proj gemm). 17,301,504 B (33792 rows x 512B).
  u16*   w1h     = (u16*)(ws + 67108864);
  u16*   w1l     = w1h + 32768;
  u16*   attn_s  = (u16*)(ws + 67108864);
  u16*   qw_bf   = (u16*)(ws + 84410368);            //  3,145,728 B
  u16*   pw_bf   = (u16*)(ws + 87556096);            //  1,048,576 B
  int*   routes  = (int*)(ws + 88604672);            //    131,072 B
  float* pmaxp   = (float*)(ws + 88735744);          //    131,072 B
  int*   sorted  = (int*)(ws + 88866816);            //    135,168 B (33792 slots)
  int*   rank    = (int*)(ws + 89001984);            //    131,072 B
  int*   counts  = (int*)(ws + 89133056);
  int*   cursors = (int*)(ws + 89133056 + 32);
  int*   offs    = (int*)(ws + 89133056 + 64);

  k_prep<<<2210, 256, 0, stream>>>(qkvw, qw_bf, projw, pw_bf, rw1, w1h, w1l,
                                   sorted, counts, cursors);
  k_router<<<512, 256, 0, stream>>>(x, w1h, w1l, rb1, rw2, rb2, routes, pmaxp, counts, x_bf);
  k_scatter<<<128, 256, 0, stream>>>(routes, counts, cursors, sorted, rank, offs);
  k_gemm<768, false, 6, 1584><<<dim3(6, 264), 256, 0, stream>>>(
      x_bf, qw_bf, qkvb, sorted, offs, nullptr, qkv_bf, nullptr);
  k_attn<<<4096, 64, 0, stream>>>(qkv_bf, rank, attn_s);        // overwrites w1 split (dead)
  k_gemm<256, true, 2, 528><<<dim3(2, 264), 256, 0, stream>>>(
      attn_s, pw_bf, projb, sorted, offs, pmaxp, nullptr, out);
}

// Round 3
// 195.983 us; speedup vs baseline: 1.1465x; 1.0070x over previous
//
#include <hip/hip_runtime.h>
#include <hip/hip_bf16.h>

typedef unsigned short u16;
typedef unsigned int u32;
typedef __attribute__((ext_vector_type(8))) short short8;   // 8 bf16 (4 VGPRs) MFMA operand
typedef __attribute__((ext_vector_type(4))) float f32x4;    // MFMA 16x16 accumulator

#define T_TOK 32768
#define SCALE_ATT 0.17677669529663687f   // 32^-0.5

__device__ __forceinline__ u16 f2bf(float f){
  u32 u = __float_as_uint(f);
  u32 r = u + 0x7fffu + ((u >> 16) & 1u);   // RTN-even
  return (u16)(r >> 16);
}
__device__ __forceinline__ float bf2f(u16 h){
  return __uint_as_float(((u32)h) << 16);
}

// XCD-chunked bijective block swizzle (nwg % 8 == 0): consecutive logical
// blocks land on the SAME XCD so shared operand panels hit its private L2.
__device__ __forceinline__ int xcd_swz(int flat, int nwg){
  return (flat & 7) * (nwg >> 3) + (flat >> 3);
}

// ---------------- fused prep: weight cvt + w1 split + sorted/-counts init ----
// b<1536: qkvw cvt | <2048: projw cvt | <2176: rw1 split | <2209: sorted=-1 | last: counters
__global__ __launch_bounds__(256) void k_prep(
    const float* __restrict__ qkvw, u16* __restrict__ qw_bf,
    const float* __restrict__ projw, u16* __restrict__ pw_bf,
    const float* __restrict__ rw1, u16* __restrict__ w1h, u16* __restrict__ w1l,
    int* __restrict__ sorted, int* __restrict__ counts, int* __restrict__ cursors)
{
  int b = blockIdx.x, tid = threadIdx.x;
  if (b < 1536){
    int i = b * 256 + tid;                       // < 393216 float4
    float4 v = ((const float4*)qkvw)[i];
    ushort4 o;
    o.x = f2bf(v.x); o.y = f2bf(v.y); o.z = f2bf(v.z); o.w = f2bf(v.w);
    ((ushort4*)qw_bf)[i] = o;
  } else if (b < 2048){
    int i = (b - 1536) * 256 + tid;              // < 131072 float4
    float4 v = ((const float4*)projw)[i];
    ushort4 o;
    o.x = f2bf(v.x); o.y = f2bf(v.y); o.z = f2bf(v.z); o.w = f2bf(v.w);
    ((ushort4*)pw_bf)[i] = o;
  } else if (b < 2176){
    int i = (b - 2048) * 256 + tid;              // < 32768
    float v = rw1[i];
    u16 h = f2bf(v);
    w1h[i] = h;
    w1l[i] = f2bf(v - bf2f(h));                  // exact residual in fp32
  } else if (b < 2209){
    int i = (b - 2176) * 256 + tid;              // < 8448 int4 = 33792 ints
    int4 m1 = {-1, -1, -1, -1};
    ((int4*)sorted)[i] = m1;
  } else {
    if (tid < 8){ counts[tid] = 0; cursors[tid] = 0; }
  }
}

// ---------------- MFMA router (split-bf16 "bf16x3") ----------------
// h = relu(x@w1^T+b1) via MFMA: x=x_hi+x_lo, w1=w1_hi+w1_lo (bf16 pairs);
// h ~ hi*hi + hi*lo + lo*hi in fp32 accum -> logit err ~1e-6 << top-2 gap.
__global__ __launch_bounds__(256) void k_router(
    const float* __restrict__ x, const u16* __restrict__ w1h, const u16* __restrict__ w1l,
    const float* __restrict__ b1, const float* __restrict__ w2, const float* __restrict__ b2,
    int* __restrict__ routes, float* __restrict__ pmax, int* __restrict__ counts,
    u16* __restrict__ x_bf)
{
  __shared__ __align__(16) char smem[64*132*4];   // 33792 B
  u16* Ah = (u16*)smem;          // 64 x 40
  u16* Al = Ah + 2560;           // 64 x 40
  u16* Bh = Al + 2560;           // 128 x 40
  u16* Bl = Bh + 5120;           // 128 x 40
  float* Hs = (float*)smem;      // overlay after MFMA: 64 x 132
  __shared__ int lhist[8];

  int tid = threadIdx.x;
  int t0 = blockIdx.x * 64;
  int wv = tid >> 6, lane = tid & 63, quad = lane >> 4, l16 = lane & 15;
  if (tid < 8) lhist[tid] = 0;

  int arow = tid >> 2, acg = tid & 3;        // A staging: 64 rows x 4 col-groups of 8
  int brow = tid >> 1, bhalf = tid & 1;      // B staging: 128 rows x 2 halves of 16

  f32x4 acc[4][2];
  #pragma unroll
  for (int i = 0; i < 4; ++i)
    #pragma unroll
    for (int j = 0; j < 2; ++j)
      #pragma unroll
      for (int rr = 0; rr < 4; ++rr) acc[i][j][rr] = 0.f;

  for (int kt = 0; kt < 8; ++kt){
    const float* gx = x + (size_t)(t0 + arow) * 256 + kt * 32 + acg * 8;
    float4 v0 = *(const float4*)gx;
    float4 v1 = *(const float4*)(gx + 4);
    ushort4 h0, h1, l0, l1;
    h0.x = f2bf(v0.x); h0.y = f2bf(v0.y); h0.z = f2bf(v0.z); h0.w = f2bf(v0.w);
    h1.x = f2bf(v1.x); h1.y = f2bf(v1.y); h1.z = f2bf(v1.z); h1.w = f2bf(v1.w);
    l0.x = f2bf(v0.x - bf2f(h0.x)); l0.y = f2bf(v0.y - bf2f(h0.y));
    l0.z = f2bf(v0.z - bf2f(h0.z)); l0.w = f2bf(v0.w - bf2f(h0.w));
    l1.x = f2bf(v1.x - bf2f(h1.x)); l1.y = f2bf(v1.y - bf2f(h1.y));
    l1.z = f2bf(v1.z - bf2f(h1.z)); l1.w = f2bf(v1.w - bf2f(h1.w));
    u16* gxb = x_bf + (size_t)(t0 + arow) * 256 + kt * 32 + acg * 8;
    *(ushort4*)gxb = h0; *(ushort4*)(gxb + 4) = h1;
    const u16* gwh = w1h + (size_t)brow * 256 + kt * 32 + bhalf * 16;
    const u16* gwl = w1l + (size_t)brow * 256 + kt * 32 + bhalf * 16;
    uint4 wh0 = *(const uint4*)gwh;
    uint4 wh1 = *(const uint4*)(gwh + 8);
    uint4 wl0 = *(const uint4*)gwl;
    uint4 wl1 = *(const uint4*)(gwl + 8);
    __syncthreads();
    *(ushort4*)&Ah[arow*40 + acg*8    ] = h0;
    *(ushort4*)&Ah[arow*40 + acg*8 + 4] = h1;
    *(ushort4*)&Al[arow*40 + acg*8    ] = l0;
    *(ushort4*)&Al[arow*40 + acg*8 + 4] = l1;
    *(uint4*)&Bh[brow*40 + bhalf*16    ] = wh0;
    *(uint4*)&Bh[brow*40 + bhalf*16 + 8] = wh1;
    *(uint4*)&Bl[brow*40 + bhalf*16    ] = wl0;
    *(uint4*)&Bl[brow*40 + bhalf*16 + 8] = wl1;
    __syncthreads();
    short8 ah[4], al[4], bhf[2], blf[2];
    #pragma unroll
    for (int i = 0; i < 4; ++i){
      ah[i] = *(const short8*)&Ah[(i*16 + l16)*40 + quad*8];
      al[i] = *(const short8*)&Al[(i*16 + l16)*40 + quad*8];
    }
    #pragma unroll
    for (int j = 0; j < 2; ++j){
      bhf[j] = *(const short8*)&Bh[(wv*32 + j*16 + l16)*40 + quad*8];
      blf[j] = *(const short8*)&Bl[(wv*32 + j*16 + l16)*40 + quad*8];
    }
    #pragma unroll
    for (int i = 0; i < 4; ++i)
      #pragma unroll
      for (int j = 0; j < 2; ++j){
        acc[i][j] = __builtin_amdgcn_mfma_f32_16x16x32_bf16(ah[i], bhf[j], acc[i][j], 0, 0, 0);
        acc[i][j] = __builtin_amdgcn_mfma_f32_16x16x32_bf16(ah[i], blf[j], acc[i][j], 0, 0, 0);
        acc[i][j] = __builtin_amdgcn_mfma_f32_16x16x32_bf16(al[i], bhf[j], acc[i][j], 0, 0, 0);
      }
  }
  __syncthreads();   // all frag reads done before Hs overlay

  #pragma unroll
  for (int i = 0; i < 4; ++i)
    #pragma unroll
    for (int j = 0; j < 2; ++j){
      int col = wv*32 + j*16 + l16;
      float bb = b1[col];
      #pragma unroll
      for (int rr = 0; rr < 4; ++rr){
        float h = acc[i][j][rr] + bb;
        Hs[(i*16 + quad*4 + rr)*132 + col] = h > 0.f ? h : 0.f;
      }
    }
  __syncthreads();

  // logits + softmax: 8 lanes per token (e = tid&7), 32 tokens/pass (fp32)
  #pragma unroll
  for (int pass = 0; pass < 2; ++pass){
    int mtok = (tid >> 3) + pass * 32;
    int e = tid & 7;
    const float4* w2r = (const float4*)(w2 + e * 128);
    float l = b2[e];
    #pragma unroll
    for (int k4 = 0; k4 < 32; ++k4){
      float4 w = w2r[k4];
      int k = k4 * 4;
      l = fmaf(Hs[mtok*132+k  ], w.x, l);
      l = fmaf(Hs[mtok*132+k+1], w.y, l);
      l = fmaf(Hs[mtok*132+k+2], w.z, l);
      l = fmaf(Hs[mtok*132+k+3], w.w, l);
    }
    float mv = l; int mi = e;
    #pragma unroll
    for (int off = 1; off < 8; off <<= 1){
      float ov = __shfl_xor(mv, off, 64);
      int   oi = __shfl_xor(mi, off, 64);
      if (ov > mv || (ov == mv && oi < mi)){ mv = ov; mi = oi; }
    }
    float sum = expf(l - mv);
    #pragma unroll
    for (int off = 1; off < 8; off <<= 1) sum += __shfl_xor(sum, off, 64);
    if (e == 0){
      int t = t0 + mtok;
      routes[t] = mi;
      pmax[t] = 1.0f / sum;
      atomicAdd(&lhist[mi], 1);
    }
  }
  __syncthreads();
  if (tid < 8 && lhist[tid] > 0) atomicAdd(&counts[tid], lhist[tid]);
}

// ---------------- scatter (offsets fused: every block recomputes the 8-entry
// prefix from counts; block 0 publishes offs). sorted pre-filled -1 by k_prep.
__global__ __launch_bounds__(256) void k_scatter(
    const int* __restrict__ routes, const int* __restrict__ counts,
    int* __restrict__ cursors, int* __restrict__ sorted, int* __restrict__ rank,
    int* __restrict__ offs)
{
  __shared__ int lc[8], lb[8], so[9];
  int tid = threadIdx.x;
  if (tid == 0){
    int o = 0; so[0] = 0;
    #pragma unroll
    for (int e = 0; e < 8; ++e){ o += ((counts[e] + 127) >> 7) << 7; so[e+1] = o; }
  }
  if (tid < 8) lc[tid] = 0;
  __syncthreads();
  int t = blockIdx.x * 256 + tid;
  int e = routes[t];
  int rl = atomicAdd(&lc[e], 1);             // LDS atomic
  __syncthreads();
  if (tid < 8 && lc[tid] > 0) lb[tid] = atomicAdd(&cursors[tid], lc[tid]);
  __syncthreads();
  int pos = so[e] + lb[e] + rl;
  sorted[pos] = t;
  rank[t] = pos;
  if (blockIdx.x == 0 && tid < 9) offs[tid] = so[tid];
}

// ---------------- grouped MoE GEMM: out[t] = A_sorted @ W[e]^T + bias[e] ----------------
// Chunk staging (R8) + XCD-chunked swizzle (R10). For !PROJ, A is read
// DIRECTLY in token order via sorted[] indirection; epilogue applies 2D RoPE
// to Q,K, folds SCALE_ATT into Q (R9), and writes qkv in HEAD-MAJOR WINDOWED
// layout [sel][head][win][n][32ch] (R11) so k_attn's fragment loads are fully
// coalesced (wave = 1KB contiguous). Token t -> win/n is pure bit-mixing.
#define ASTR 56   // LDS row stride (elems): 112B, 16B-aligned, 2-way banking
template<int NOUT, bool PROJ, int NB, int NWG>
__global__ __launch_bounds__(256) void k_gemm(
    const u16* __restrict__ A, const u16* __restrict__ W,
    const float* __restrict__ bias, const int* __restrict__ sidx,
    const int* __restrict__ offs, const float* __restrict__ pmax,
    u16* __restrict__ outb, float* __restrict__ outf)
{
  __shared__ __align__(16) u16 As[128 * ASTR];
  __shared__ __align__(16) u16 Bs[128 * ASTR];
  int tid = threadIdx.x;
  int flat = blockIdx.y * NB + blockIdx.x;     // hw dispatch order (x fastest)
  int logical = xcd_swz(flat, NWG);
  int m0 = (logical / NB) * 128;
  int n0 = (logical % NB) * 128;
  int total = offs[8];
  if (m0 >= total) return;
  int e = 0;
  #pragma unroll
  for (int i = 1; i < 8; ++i) if (m0 >= offs[i]) e = i;

  int wv = tid >> 6, lane = tid & 63, quad = lane >> 4, l16 = lane & 15;
  int wrow = (wv >> 1) * 64, wcol = (wv & 1) * 64;

  // chunk staging: thread handles (row0, c0) and (row0+64, c0); 16B each
  int row0 = tid >> 2, c0 = tid & 3;
  const u16 *aptr0, *aptr1;
  if (PROJ){
    aptr0 = A + (size_t)(m0 + row0) * 256 + c0 * 8;
    aptr1 = aptr0 + (size_t)64 * 256;
  } else {
    int tA0 = sidx[m0 + row0];      if (tA0 < 0) tA0 = 0;   // clamp: row discarded in epilogue
    int tA1 = sidx[m0 + row0 + 64]; if (tA1 < 0) tA1 = 0;
    aptr0 = A + (size_t)tA0 * 256 + c0 * 8;
    aptr1 = A + (size_t)tA1 * 256 + c0 * 8;
  }
  int pc = (row0 >> 4) + (row0 & 15) * 4;          // permuted col within 64-half
  const u16* bptr0 = W + ((size_t)e * NOUT + n0 + pc) * 256 + c0 * 8;
  const u16* bptr1 = W + ((size_t)e * NOUT + n0 + 64 + pc) * 256 + c0 * 8;

  f32x4 acc[4][4];
  #pragma unroll
  for (int i = 0; i < 4; ++i)
    #pragma unroll
    for (int j = 0; j < 4; ++j)
      #pragma unroll
      for (int r = 0; r < 4; ++r) acc[i][j][r] = 0.f;

  // prologue: prefetch k-tile 0
  uint4 a0 = *(const uint4*)aptr0, a1 = *(const uint4*)aptr1;
  uint4 b0 = *(const uint4*)bptr0, b1 = *(const uint4*)bptr1;

  for (int kt = 0; kt < 8; ++kt){
    __syncthreads();
    *(uint4*)&As[ row0      *ASTR + c0*8] = a0;
    *(uint4*)&As[(row0 + 64)*ASTR + c0*8] = a1;
    *(uint4*)&Bs[ row0      *ASTR + c0*8] = b0;
    *(uint4*)&Bs[(row0 + 64)*ASTR + c0*8] = b1;
    __syncthreads();
    if (kt < 7){                       // prefetch kt+1; overlaps frag reads + MFMA
      a0 = *(const uint4*)(aptr0 + (kt+1)*32);
      a1 = *(const uint4*)(aptr1 + (kt+1)*32);
      b0 = *(const uint4*)(bptr0 + (kt+1)*32);
      b1 = *(const uint4*)(bptr1 + (kt+1)*32);
    }
    short8 af[4], bfv[4];
    #pragma unroll
    for (int i = 0; i < 4; ++i)
      af[i] = *(const short8*)&As[(wrow + i*16 + l16)*ASTR + quad*8];
    #pragma unroll
    for (int j = 0; j < 4; ++j)
      bfv[j] = *(const short8*)&Bs[(wcol + j*16 + l16)*ASTR + quad*8];
    #pragma unroll
    for (int i = 0; i < 4; ++i)
      #pragma unroll
      for (int j = 0; j < 4; ++j)
        acc[i][j] = __builtin_amdgcn_mfma_f32_16x16x32_bf16(af[i], bfv[j], acc[i][j], 0, 0, 0);
  }

  // epilogue: frag j of lane l16 = output col n0+wcol+l16*4+j (contiguous)
  float4 bj4 = *(const float4*)&bias[e*NOUT + n0 + wcol + l16*4];
  if (PROJ){
    #pragma unroll
    for (int i = 0; i < 4; ++i){
      #pragma unroll
      for (int ri = 0; ri < 4; ++ri){
        int row = wrow + i*16 + quad*4 + ri;        // C/D: row=quad*4+reg [m89]
        int t = sidx[m0 + row];
        if (t < 0) continue;
        float pm = pmax[t];
        float4 ov;
        ov.x = (acc[i][0][ri] + bj4.x) * pm;
        ov.y = (acc[i][1][ri] + bj4.y) * pm;
        ov.z = (acc[i][2][ri] + bj4.z) * pm;
        ov.w = (acc[i][3][ri] + bj4.w) * pm;
        *(float4*)&outf[(size_t)t * NOUT + n0 + wcol + l16*4] = ov;
      }
    }
  } else {
    // qkv: cols [0,256)=Q (rotate + scale), [256,512)=K (rotate), [512,768)=V
    int col0 = n0 + wcol + l16*4;
    bool isqk = (col0 < 512);
    float inv0 = 0.f, inv1 = 0.f;
    float qsc = (col0 < 256) ? SCALE_ATT : 1.0f;
    if (isqk){
      int p0 = (col0 & 15) >> 1;                    // pair idx within half: 0,2,4,6
      inv0 = __expf(-1.1512925465f * (float)p0);    // 10000^(-p0/8)
      inv1 = inv0 * 0.31622776601683794f;           // * 10^-0.5 -> 10000^(-(p0+1)/8)
    }
    int sel  = col0 >> 8;                            // 0=Q 1=K 2=V
    int head = (col0 >> 5) & 7;
    int ch   = col0 & 31;                            // multiple of 4
    size_t hb = ((size_t)(sel * 8 + head) * 512) * 2048 + ch;
    #pragma unroll
    for (int i = 0; i < 4; ++i){
      #pragma unroll
      for (int ri = 0; ri < 4; ++ri){
        int row = wrow + i*16 + quad*4 + ri;
        int t = sidx[m0 + row];
        if (t < 0) continue;
        float vx = acc[i][0][ri] + bj4.x;
        float vy = acc[i][1][ri] + bj4.y;
        float vz = acc[i][2][ri] + bj4.z;
        float vw = acc[i][3][ri] + bj4.w;
        if (isqk){
          // token window coords: row half = (t>>6)&7, col half = t&7
          float pos = (float)((col0 & 16) ? (t & 7) : ((t >> 6) & 7));
          float a0r = pos * inv0, a1r = pos * inv1;
          float s0, c0s, s1, c1s;
          __sincosf(a0r, &s0, &c0s);
          __sincosf(a1r, &s1, &c1s);
          float r0 = (vx*c0s - vy*s0) * qsc;
          float r1 = (vx*s0 + vy*c0s) * qsc;
          float r2 = (vz*c1s - vw*s1) * qsc;
          float r3 = (vz*s1 + vw*c1s) * qsc;
          vx = r0; vy = r1; vz = r2; vw = r3;
        }
        // head-major windowed address: win = b*64+wy*8+wx, n = iy*8+ix
        int win = (t >> 12) * 64 + ((t >> 9) & 7) * 8 + ((t >> 3) & 7);
        int n   = ((t >> 6) & 7) * 8 + (t & 7);
        uint2 ov;
        ov.x = (u32)f2bf(vx) | ((u32)f2bf(vy) << 16);
        ov.y = (u32)f2bf(vz) | ((u32)f2bf(vw) << 16);
        *(uint2*)&outb[hb + (size_t)win * 2048 + n * 32] = ov;
      }
    }
  }
}

// ---------------- MFMA windowed attention (RoPE pre-applied in QKV GEMM) ----------------
// One 64-thread block per (head, window). qkv is head-major windowed, so every
// Q/K fragment load and V sweep is a fully-dense 1KB wave access. rank[] is
// prefetched at the top (broadcast loads hidden under QK). Row-sums via
// shfl_xor. LDS 13824B -> 11 blocks/CU.
__global__ __launch_bounds__(64, 3) void k_attn(const u16* __restrict__ qkv,
                                                const int* __restrict__ rank,
                                                u16* __restrict__ attn_s)
{
  __shared__ __align__(16) u16 Ps[64*72];   // P bf16, permuted cols, stride 72
  __shared__ __align__(16) u16 Vt[32*72];   // V^T: Vt[d][pi(n)]

  int lane = threadIdx.x;
  int quad = lane >> 4, l16 = lane & 15;
  int wh = xcd_swz(blockIdx.x, 4096);
  int head = wh >> 9, win = wh & 511;        // head-major: consecutive blocks walk wins
  int b = win >> 6, wy = (win >> 3) & 7, wx = win & 7;
  int tb = b*4096 + wy*512 + wx*8;           // token(n) = tb + (n>>3)*64 + (n&7)

  const u16* qbase = qkv + (size_t)(head * 512 + win) * 2048;
  const u16* kbase = qbase + (size_t)8 * 512 * 2048;
  const u16* vbase = qbase + (size_t)16 * 512 * 2048;

  // rank prefetch: 16 broadcast loads, latency hidden under QK^T
  int rk[4][4];
  #pragma unroll
  for (int i = 0; i < 4; ++i)
    #pragma unroll
    for (int rr = 0; rr < 4; ++rr){
      int m = i*16 + quad*4 + rr;
      rk[i][rr] = rank[tb + (m >> 3) * 64 + (m & 7)];
    }

  // Q/K frags: wave covers 1KB contiguous per load (token n = i*16+l16, ch quad*8)
  short8 qf[4], kf[4];
  #pragma unroll
  for (int i = 0; i < 4; ++i){
    qf[i] = *(const short8*)(qbase + (i*16 + l16)*32 + quad*8);
    kf[i] = *(const short8*)(kbase + (i*16 + l16)*32 + quad*8);
  }
  // V: 4 x 1KB dense sweeps; lane holds token n = h*16+l16, ch quad*8..+7
  uint4 va[4];
  #pragma unroll
  for (int h = 0; h < 4; ++h)
    va[h] = *(const uint4*)(vbase + h*512 + l16*32 + quad*8);

  // S = Q K^T (scale already folded into Q)
  f32x4 sa[4][4];
  #pragma unroll
  for (int i = 0; i < 4; ++i)
    #pragma unroll
    for (int j = 0; j < 4; ++j){
      #pragma unroll
      for (int rr = 0; rr < 4; ++rr) sa[i][j][rr] = 0.f;
      sa[i][j] = __builtin_amdgcn_mfma_f32_16x16x32_bf16(qf[i], kf[j], sa[i][j], 0, 0, 0);
    }

  // P = exp(S) -> bf16 -> Ps (permuted col pi(n) = (n&15)*4 + (n>>4));
  // row-sum accumulated per (i,rr) then shfl-reduced over l16 (cols).
  f32x4 rs[4];
  #pragma unroll
  for (int i = 0; i < 4; ++i)
    #pragma unroll
    for (int rr = 0; rr < 4; ++rr){
      float e0 = __expf(sa[i][0][rr]);
      float e1 = __expf(sa[i][1][rr]);
      float e2 = __expf(sa[i][2][rr]);
      float e3 = __expf(sa[i][3][rr]);
      rs[i][rr] = (e0 + e1) + (e2 + e3);
      uint2 pk;
      pk.x = (u32)f2bf(e0) | ((u32)f2bf(e1) << 16);
      pk.y = (u32)f2bf(e2) | ((u32)f2bf(e3) << 16);
      *(uint2*)&Ps[(i*16 + quad*4 + rr)*72 + l16*4] = pk;
    }
  #pragma unroll
  for (int i = 0; i < 4; ++i)
    #pragma unroll
    for (int rr = 0; rr < 4; ++rr){
      #pragma unroll
      for (int off = 1; off < 16; off <<= 1)
        rs[i][rr] += __shfl_xor(rs[i][rr], off, 64);
    }

  // stage V transposed+permuted: Vt[d][pi(n)] = V[n][d]; pi(n) = l16*4 + h
  // (16 lanes of a quad write 2B at stride 8B -> distinct banks)
  u32* vu = (u32*)va;
  #pragma unroll
  for (int h = 0; h < 4; ++h){
    int pn = l16 * 4 + h;
    #pragma unroll
    for (int w = 0; w < 4; ++w){
      u32 vv = vu[h*4 + w];
      Vt[(quad*8 + 2*w    )*72 + pn] = (u16)(vv & 0xffff);
      Vt[(quad*8 + 2*w + 1)*72 + pn] = (u16)(vv >> 16);
    }
  }

  // PV: P A-frags from Ps, V B-frags from Vt (both in pi-space), 2 k-steps of 32.
  f32x4 oa[4][2];
  #pragma unroll
  for (int i = 0; i < 4; ++i)
    #pragma unroll
    for (int rr = 0; rr < 4; ++rr){ oa[i][0][rr] = 0.f; oa[i][1][rr] = 0.f; }
  #pragma unroll
  for (int ks = 0; ks < 2; ++ks){
    short8 vf0 = *(const short8*)&Vt[(     l16)*72 + ks*32 + quad*8];
    short8 vf1 = *(const short8*)&Vt[(16 + l16)*72 + ks*32 + quad*8];
    #pragma unroll
    for (int i = 0; i < 4; ++i){
      short8 pf = *(const short8*)&Ps[(i*16 + l16)*72 + ks*32 + quad*8];
      oa[i][0] = __builtin_amdgcn_mfma_f32_16x16x32_bf16(pf, vf0, oa[i][0], 0, 0, 0);
      oa[i][1] = __builtin_amdgcn_mfma_f32_16x16x32_bf16(pf, vf1, oa[i][1], 0, 0, 0);
    }
  }

  // epilogue: O[m][d] = oa/rowsum; store bf16 at sorted position rank[token]
  #pragma unroll
  for (int i = 0; i < 4; ++i)
    #pragma unroll
    for (int rr = 0; rr < 4; ++rr){
      float inv = __builtin_amdgcn_rcpf(rs[i][rr]);
      int pos = rk[i][rr];
      u16* op = attn_s + (size_t)pos * 256 + head * 32 + l16;
      op[0]  = f2bf(oa[i][0][rr] * inv);
      op[16] = f2bf(oa[i][1][rr] * inv);
    }
}

// ---------------- launch ----------------
extern "C" void kernel_launch(void* const* d_in, const int* in_sizes, int n_in,
                              void* d_out, int out_size, void* d_ws, size_t ws_size,
                              hipStream_t stream){
  const float* x     = (const float*)d_in[0];
  const float* rw1   = (const float*)d_in[1];
  const float* rb1   = (const float*)d_in[2];
  const float* rw2   = (const float*)d_in[3];
  const float* rb2   = (const float*)d_in[4];
  const float* qkvw  = (const float*)d_in[5];
  const float* qkvb  = (const float*)d_in[6];
  const float* projw = (const float*)d_in[7];
  const float* projb = (const float*)d_in[8];
  float* out = (float*)d_out;

  char* ws = (char*)d_ws;
  u16*   x_bf    = (u16*)(ws);                       // 16,777,216 B
  u16*   qkv_bf  = (u16*)(ws + 16777216);            // 50,331,648 B (head-major windowed)
  // shared region (disjoint lifetimes): w1 split (router) -> attn_s (attn +
  // proj gemm). 17,301,504 B (33792 rows x 512B).
  u16*   w1h     = (u16*)(ws + 67108864);
  u16*   w1l     = w1h + 32768;
  u16*   attn_s  = (u16*)(ws + 67108864);
  u16*   qw_bf   = (u16*)(ws + 84410368);            //  3,145,728 B
  u16*   pw_bf   = (u16*)(ws + 87556096);            //  1,048,576 B
  int*   routes  = (int*)(ws + 88604672);            //    131,072 B
  float* pmaxp   = (float*)(ws + 88735744);          //    131,072 B
  int*   sorted  = (int*)(ws + 88866816);            //    135,168 B (33792 slots)
  int*   rank    = (int*)(ws + 89001984);            //    131,072 B
  int*   counts  = (int*)(ws + 89133056);
  int*   cursors = (int*)(ws + 89133056 + 32);
  int*   offs    = (int*)(ws + 89133056 + 64);

  k_prep<<<2210, 256, 0, stream>>>(qkvw, qw_bf, projw, pw_bf, rw1, w1h, w1l,
                                   sorted, counts, cursors);
  k_router<<<512, 256, 0, stream>>>(x, w1h, w1l, rb1, rw2, rb2, routes, pmaxp, counts, x_bf);
  k_scatter<<<128, 256, 0, stream>>>(routes, counts, cursors, sorted, rank, offs);
  k_gemm<768, false, 6, 1584><<<dim3(6, 264), 256, 0, stream>>>(
      x_bf, qw_bf, qkvb, sorted, offs, nullptr, qkv_bf, nullptr);
  k_attn<<<4096, 64, 0, stream>>>(qkv_bf, rank, attn_s);        // overwrites w1 split (dead)
  k_gemm<256, true, 2, 528><<<dim3(2, 264), 256, 0, stream>>>(
      attn_s, pw_bf, projb, sorted, offs, pmaxp, nullptr, out);
}